// Round 3
// baseline (1078.076 us; speedup 1.0000x reference)
//
#include <hip/hip_runtime.h>
#include <math.h>

#define NNODES 100000
#define NEDGES 1600000
#define DF 128
#define ED 16
#define NBLK_SCAN ((NNODES + 255) / 256)   // 391
#define GCHUNK 512                         // edges per block in k_gates2

// ---------------- transpose edge-MLP layer-1 weights: t[j*16+k] = w[k*128+j]
__global__ void k_transpose(const float* __restrict__ wa, const float* __restrict__ wb,
                            float* __restrict__ ta, float* __restrict__ tb) {
    int t = blockIdx.x * blockDim.x + threadIdx.x;
    if (t >= 2 * 2048) return;
    const float* src = (t < 2048) ? wa : wb;
    float*       dst = (t < 2048) ? ta : tb;
    int i = t & 2047;
    int j = i >> 4, k = i & 15;
    dst[i] = src[k * DF + j];
}

// ---------------- deg init (self-loop weight 1) + zero in-degree counters
__global__ void k_deg_init(float* __restrict__ d1, float* __restrict__ d2,
                           int* __restrict__ cnt) {
    int i = blockIdx.x * blockDim.x + threadIdx.x;
    if (i < NNODES) { d1[i] = 1.f; d2[i] = 1.f; cnt[i] = 0; }
}

// ---------------- edge gates, register-resident weights.
// Threads: 32 j-lanes x 8 edge-rows. Each thread owns 4 hidden columns
// (64 weight floats in VGPRs). Two passes (layer1/layer2) reuse the regs.
__global__ __launch_bounds__(256) void k_gates2(
    const float* __restrict__ ea, const int* __restrict__ ei,
    const float* __restrict__ w1t1, const float* __restrict__ b11,
    const float* __restrict__ w21,  const float* __restrict__ b21,
    const float* __restrict__ w1t2, const float* __restrict__ b12,
    const float* __restrict__ w22,  const float* __restrict__ b22,
    float* __restrict__ g1, float* __restrict__ g2,
    float* __restrict__ deg1, float* __restrict__ deg2,
    int* __restrict__ cnt) {
    __shared__ __align__(16) float sA[GCHUNK * 16];   // 32 KB edge attrs
    __shared__ float zb1[GCHUNK], zb2[GCHUNK];        // 4 KB
    int t = threadIdx.x;
    int jl = t & 31, er = t >> 5;
    size_t ebase = (size_t)blockIdx.x * GCHUNK;

    // stage edge attrs (coalesced float4)
    const float4* src = (const float4*)(ea + ebase * ED);
    for (int i = t; i < GCHUNK * 4; i += 256) ((float4*)sA)[i] = src[i];
    __syncthreads();

    for (int layer = 0; layer < 2; layer++) {
        const float* wt = layer ? w1t2 : w1t1;
        const float* bb = layer ? b12 : b11;
        const float* w2 = layer ? w22 : w21;
        float* zb = layer ? zb2 : zb1;

        // my 4 hidden columns -> registers
        float wr[4][16];
        float wb[4], w2r[4];
#pragma unroll
        for (int c = 0; c < 4; c++) {
            int j = jl * 4 + c;
            const float4* s = (const float4*)(wt + j * 16);
            float4 v0 = s[0], v1 = s[1], v2 = s[2], v3 = s[3];
            wr[c][0] = v0.x; wr[c][1] = v0.y; wr[c][2]  = v0.z; wr[c][3]  = v0.w;
            wr[c][4] = v1.x; wr[c][5] = v1.y; wr[c][6]  = v1.z; wr[c][7]  = v1.w;
            wr[c][8] = v2.x; wr[c][9] = v2.y; wr[c][10] = v2.z; wr[c][11] = v2.w;
            wr[c][12] = v3.x; wr[c][13] = v3.y; wr[c][14] = v3.z; wr[c][15] = v3.w;
            wb[c] = bb[j]; w2r[c] = w2[j];
        }

        for (int it = 0; it < GCHUNK / 8; it++) {
            int el = it * 8 + er;
            const float4* a4 = (const float4*)(sA + el * 16);
            float4 a0 = a4[0], a1 = a4[1], a2 = a4[2], a3 = a4[3];
            float z = 0.f;
#pragma unroll
            for (int c = 0; c < 4; c++) {
                float h = wb[c]
                    + a0.x * wr[c][0]  + a0.y * wr[c][1]  + a0.z * wr[c][2]  + a0.w * wr[c][3]
                    + a1.x * wr[c][4]  + a1.y * wr[c][5]  + a1.z * wr[c][6]  + a1.w * wr[c][7]
                    + a2.x * wr[c][8]  + a2.y * wr[c][9]  + a2.z * wr[c][10] + a2.w * wr[c][11]
                    + a3.x * wr[c][12] + a3.y * wr[c][13] + a3.z * wr[c][14] + a3.w * wr[c][15];
                z += fmaxf(h, 0.f) * w2r[c];
            }
            // reduce across the 32 j-lanes (width-32 keeps er halves separate)
#pragma unroll
            for (int m = 16; m >= 1; m >>= 1) z += __shfl_xor(z, m, 32);
            if (jl == 0) zb[el] = z;
        }
    }
    __syncthreads();

    // finalize: sigmoid + store gates + degree/count atomics (coalesced)
    for (int i = t; i < GCHUNK; i += 256) {
        size_t e = ebase + i;
        float ga = 1.f / (1.f + expf(-zb1[i]));
        float gb = 1.f / (1.f + expf(-zb2[i]));
        g1[e] = ga; g2[e] = gb;
        int c = ei[NEDGES + e];
        atomicAdd(&deg1[c], ga);
        atomicAdd(&deg2[c], gb);
        atomicAdd(&cnt[c], 1);
    }
}

// ---------------- deg -> rsqrt(deg) in place (deg >= 1 always)
__global__ void k_rsqrt(float* __restrict__ d1, float* __restrict__ d2) {
    int i = blockIdx.x * blockDim.x + threadIdx.x;
    if (i < NNODES) { d1[i] = rsqrtf(d1[i]); d2[i] = rsqrtf(d2[i]); }
}

// ---------------- scan phase 1: per-256-block exclusive scan + block sums
__global__ __launch_bounds__(256) void k_scan1(const int* __restrict__ cnt,
                                               int* __restrict__ offs,
                                               int* __restrict__ partial) {
    __shared__ int s[256];
    int t = threadIdx.x;
    int gid = blockIdx.x * 256 + t;
    int own = (gid < NNODES) ? cnt[gid] : 0;
    s[t] = own;
    __syncthreads();
    for (int off = 1; off < 256; off <<= 1) {
        int v = (t >= off) ? s[t - off] : 0;
        __syncthreads();
        s[t] += v;
        __syncthreads();
    }
    if (gid < NNODES) offs[gid] = s[t] - own;   // exclusive
    if (t == 255) partial[blockIdx.x] = s[255];
}

// ---------------- scan phase 2: single block scans the block sums (exclusive)
__global__ __launch_bounds__(512) void k_scan2(int* __restrict__ partial) {
    __shared__ int s[512];
    int t = threadIdx.x;
    int own = (t < NBLK_SCAN) ? partial[t] : 0;
    s[t] = own;
    __syncthreads();
    for (int off = 1; off < 512; off <<= 1) {
        int v = (t >= off) ? s[t - off] : 0;
        __syncthreads();
        s[t] += v;
        __syncthreads();
    }
    if (t < NBLK_SCAN) partial[t] = s[t] - own;  // exclusive
}

// ---------------- scan phase 3: add block offsets; init cursor; offs[N]=E
__global__ void k_scan3(int* __restrict__ offs, const int* __restrict__ partial,
                        int* __restrict__ cur) {
    int gid = blockIdx.x * blockDim.x + threadIdx.x;
    if (gid < NNODES) {
        int v = offs[gid] + partial[gid >> 8];
        offs[gid] = v;
        cur[gid] = v;
    }
    if (gid == 0) offs[NNODES] = NEDGES;
}

// ---------------- scatter edges into CSR slots + precompute per-layer norms
__global__ __launch_bounds__(256) void k_scatter(
    const int* __restrict__ ei, const float* __restrict__ g1,
    const float* __restrict__ g2, const float* __restrict__ dinv1,
    const float* __restrict__ dinv2, int* __restrict__ cur,
    int* __restrict__ prow, float* __restrict__ wl1, float* __restrict__ wl2) {
    int e = blockIdx.x * 256 + threadIdx.x;
    if (e >= NEDGES) return;
    int r = ei[e], c = ei[NEDGES + e];
    int pos = atomicAdd(&cur[c], 1);
    prow[pos] = r;
    wl1[pos] = dinv1[r] * g1[e] * dinv1[c];
    wl2[pos] = dinv2[r] * g2[e] * dinv2[c];
}

// ---------------- fp32 GEMM: Y[M,128] = act(X)[M,128] @ W[128,128]
template <int RELU>
__global__ __launch_bounds__(256) void k_gemm(const float* __restrict__ X,
                                              const float* __restrict__ W,
                                              float* __restrict__ Y, int M) {
    __shared__ __align__(16) float sX[64 * 68];
    __shared__ __align__(16) float sW[64 * 132];
    int t = threadIdx.x;
    int row0 = blockIdx.x * 64;
    int tx = t & 15, ty = t >> 4;

    float acc[4][8];
#pragma unroll
    for (int i = 0; i < 4; i++)
#pragma unroll
        for (int j = 0; j < 8; j++) acc[i][j] = 0.f;

    for (int kt = 0; kt < 128; kt += 64) {
        for (int i = t; i < 1024; i += 256) {
            int r = i >> 4, c4 = i & 15;
            float4 v = make_float4(0.f, 0.f, 0.f, 0.f);
            if (row0 + r < M) v = ((const float4*)X)[(size_t)(row0 + r) * 32 + (kt >> 2) + c4];
            if (RELU) {
                v.x = fmaxf(v.x, 0.f); v.y = fmaxf(v.y, 0.f);
                v.z = fmaxf(v.z, 0.f); v.w = fmaxf(v.w, 0.f);
            }
            ((float4*)(sX + r * 68))[c4] = v;
        }
        for (int i = t; i < 2048; i += 256) {
            int r = i >> 5, c4 = i & 31;
            float4 v = ((const float4*)W)[(size_t)(kt + r) * 32 + c4];
            ((float4*)(sW + r * 132))[c4] = v;
        }
        __syncthreads();
#pragma unroll 8
        for (int k = 0; k < 64; k++) {
            float xv[4];
#pragma unroll
            for (int i = 0; i < 4; i++) xv[i] = sX[(ty * 4 + i) * 68 + k];
            float4 wA = *(const float4*)(sW + k * 132 + tx * 4);
            float4 wB = *(const float4*)(sW + k * 132 + 64 + tx * 4);
#pragma unroll
            for (int i = 0; i < 4; i++) {
                acc[i][0] += xv[i] * wA.x; acc[i][1] += xv[i] * wA.y;
                acc[i][2] += xv[i] * wA.z; acc[i][3] += xv[i] * wA.w;
                acc[i][4] += xv[i] * wB.x; acc[i][5] += xv[i] * wB.y;
                acc[i][6] += xv[i] * wB.z; acc[i][7] += xv[i] * wB.w;
            }
        }
        __syncthreads();
    }
#pragma unroll
    for (int i = 0; i < 4; i++) {
        int r = row0 + ty * 4 + i;
        if (r < M) {
            float4 o1 = make_float4(acc[i][0], acc[i][1], acc[i][2], acc[i][3]);
            float4 o2 = make_float4(acc[i][4], acc[i][5], acc[i][6], acc[i][7]);
            *(float4*)(Y + (size_t)r * 128 + tx * 4) = o1;
            *(float4*)(Y + (size_t)r * 128 + 64 + tx * 4) = o2;
        }
    }
}

// ---------------- CSR aggregation: one wave per node, register accumulation.
__global__ __launch_bounds__(256) void k_aggcsr(
    const int* __restrict__ offs, const int* __restrict__ prow,
    const float* __restrict__ wl, const float* __restrict__ dinv,
    const float* __restrict__ h, float* __restrict__ out) {
    int node = blockIdx.x * 4 + (threadIdx.x >> 6);
    if (node >= NNODES) return;
    int lane = threadIdx.x & 63;
    int beg = offs[node], end = offs[node + 1];
    float d = dinv[node];
    float2 hv = ((const float2*)h)[(size_t)node * 64 + lane];
    float2 acc;
    acc.x = d * d * hv.x;
    acc.y = d * d * hv.y;
    int   r_n = 0; float w_n = 0.f;
    if (beg < end) { r_n = prow[beg]; w_n = wl[beg]; }
    for (int e = beg; e < end; e++) {
        int   r = r_n;
        float w = w_n;
        if (e + 1 < end) { r_n = prow[e + 1]; w_n = wl[e + 1]; }
        float2 v = ((const float2*)h)[(size_t)r * 64 + lane];
        acc.x += w * v.x;
        acc.y += w * v.y;
    }
    ((float2*)out)[(size_t)node * 64 + lane] = acc;
}

extern "C" void kernel_launch(void* const* d_in, const int* in_sizes, int n_in,
                              void* d_out, int out_size, void* d_ws, size_t ws_size,
                              hipStream_t stream) {
    const float* x    = (const float*)d_in[0];
    const int*   ei   = (const int*)d_in[1];
    const float* ea   = (const float*)d_in[2];
    const float* W1   = (const float*)d_in[3];
    const float* m1w1 = (const float*)d_in[4];
    const float* m1b1 = (const float*)d_in[5];
    const float* m1w2 = (const float*)d_in[6];
    const float* m1b2 = (const float*)d_in[7];
    const float* W2   = (const float*)d_in[8];
    const float* m2w1 = (const float*)d_in[9];
    const float* m2b1 = (const float*)d_in[10];
    const float* m2w2 = (const float*)d_in[11];
    const float* m2b2 = (const float*)d_in[12];
    float* out = (float*)d_out;

    float* ws    = (float*)d_ws;
    float* g1    = ws;                               // E
    float* g2    = g1 + NEDGES;                      // E
    float* deg1  = g2 + NEDGES;                      // N
    float* deg2  = deg1 + NNODES;                    // N
    float* hbuf  = deg2 + NNODES;                    // N*128
    float* aggbf = hbuf + (size_t)NNODES * 128;      // N*128
    float* w1t1  = aggbf + (size_t)NNODES * 128;     // 2048
    float* w1t2  = w1t1 + 2048;                      // 2048
    float* wl1   = w1t2 + 2048;                      // E
    float* wl2   = wl1 + NEDGES;                     // E
    int*   cnt   = (int*)(wl2 + NEDGES);             // N (also cursor)
    int*   offs  = cnt + NNODES;                     // N+1
    int*   part  = offs + NNODES + 1;                // 1024
    int*   prow  = part + 1024;                      // E

    k_transpose<<<16, 256, 0, stream>>>(m1w1, m2w1, w1t1, w1t2);
    k_deg_init<<<(NNODES + 255) / 256, 256, 0, stream>>>(deg1, deg2, cnt);
    k_gates2<<<NEDGES / GCHUNK, 256, 0, stream>>>(ea, ei, w1t1, m1b1, m1w2, m1b2,
                                                  w1t2, m2b1, m2w2, m2b2,
                                                  g1, g2, deg1, deg2, cnt);
    k_rsqrt<<<(NNODES + 255) / 256, 256, 0, stream>>>(deg1, deg2);

    // CSR build (graph shared by both layers)
    k_scan1<<<NBLK_SCAN, 256, 0, stream>>>(cnt, offs, part);
    k_scan2<<<1, 512, 0, stream>>>(part);
    k_scan3<<<(NNODES + 255) / 256, 256, 0, stream>>>(offs, part, cnt);
    k_scatter<<<NEDGES / 256, 256, 0, stream>>>(ei, g1, g2, deg1, deg2,
                                                cnt, prow, wl1, wl2);

    // layer 1
    k_gemm<0><<<(NNODES + 63) / 64, 256, 0, stream>>>(x, W1, hbuf, NNODES);
    k_aggcsr<<<(NNODES + 3) / 4, 256, 0, stream>>>(offs, prow, wl1, deg1, hbuf, aggbf);

    // layer 2 (relu fused into GEMM load)
    k_gemm<1><<<(NNODES + 63) / 64, 256, 0, stream>>>(aggbf, W2, hbuf, NNODES);
    k_aggcsr<<<(NNODES + 3) / 4, 256, 0, stream>>>(offs, prow, wl2, deg2, hbuf, out);
}

// Round 4
// 935.894 us; speedup vs baseline: 1.1519x; 1.1519x over previous
//
#include <hip/hip_runtime.h>
#include <math.h>

#define NNODES 100000
#define NEDGES 1600000
#define DF 128
#define ED 16
#define NBLK_SCAN ((NNODES + 255) / 256)   // 391

typedef float v2f __attribute__((ext_vector_type(2)));

// ---------------- prep: interleave layer1/layer2 edge-MLP params for packed math
// wint[j*32 + 2k + L] = wL[k*128 + j]   (j in [0,128), k in [0,16), L in {0,1})
// bw2[2j + L] = bL[j] ;  bw2[256 + 2j + L] = w2L[j]
__global__ void k_prep(const float* __restrict__ m1w1, const float* __restrict__ m2w1,
                       const float* __restrict__ m1b1, const float* __restrict__ m2b1,
                       const float* __restrict__ m1w2, const float* __restrict__ m2w2,
                       float* __restrict__ wint, float* __restrict__ bw2) {
    int t = blockIdx.x * blockDim.x + threadIdx.x;
    if (t < 4096) {
        int j = t >> 5, r = t & 31;
        int k = r >> 1, L = r & 1;
        const float* src = L ? m2w1 : m1w1;
        wint[t] = src[k * DF + j];
    } else if (t < 4096 + 256) {
        int i = t - 4096;
        int j = i >> 1, L = i & 1;
        bw2[i] = L ? m2b1[j] : m1b1[j];
    } else if (t < 4096 + 512) {
        int i = t - 4096 - 256;
        int j = i >> 1, L = i & 1;
        bw2[256 + i] = L ? m2w2[j] : m1w2[j];
    }
}

// ---------------- deg init (self-loop weight 1) + zero in-degree counters
__global__ void k_deg_init(float* __restrict__ d1, float* __restrict__ d2,
                           int* __restrict__ cnt) {
    int i = blockIdx.x * blockDim.x + threadIdx.x;
    if (i < NNODES) { d1[i] = 1.f; d2[i] = 1.f; cnt[i] = 0; }
}

// ---------------- edge gates, BOTH layers packed into v_pk_fma_f32 halves.
// One edge per thread (R2 structure); weights broadcast from LDS.
__global__ __launch_bounds__(256) void k_gates3(
    const float* __restrict__ ea, const int* __restrict__ ei,
    const float* __restrict__ wint, const float* __restrict__ bw2,
    const float* __restrict__ b21, const float* __restrict__ b22,
    float* __restrict__ g1, float* __restrict__ g2,
    float* __restrict__ deg1, float* __restrict__ deg2,
    int* __restrict__ cnt) {
    __shared__ __align__(16) v2f sw[2048];          // 16 KB interleaved weights
    __shared__ __align__(16) v2f sb[128], s2[128];  // bias pairs, w2 pairs
    int t = threadIdx.x;
    for (int i = t; i < 2048; i += 256) sw[i] = ((const v2f*)wint)[i];
    if (t < 128) { sb[t] = ((const v2f*)bw2)[t]; s2[t] = ((const v2f*)(bw2 + 256))[t]; }
    __syncthreads();

    int e = blockIdx.x * 256 + t;
    if (e >= NEDGES) return;

    float a[16];
    const float4* ea4 = (const float4*)(ea + (size_t)e * ED);
#pragma unroll
    for (int q = 0; q < 4; q++) {
        float4 v = ea4[q];
        a[q*4+0] = v.x; a[q*4+1] = v.y; a[q*4+2] = v.z; a[q*4+3] = v.w;
    }

    v2f z;
    z.x = b21[0]; z.y = b22[0];
#pragma unroll 2
    for (int j = 0; j < 128; j++) {
        const v2f* wp = sw + j * 16;
        v2f h = sb[j];
#pragma unroll
        for (int k = 0; k < 16; k++) h += wp[k] * a[k];   // v_pk_fma_f32
        v2f hr = __builtin_elementwise_max(h, (v2f)(0.f)); // v_pk_max_f32
        z += hr * s2[j];                                   // v_pk_fma_f32
    }
    float ga = 1.f / (1.f + expf(-z.x));
    float gb = 1.f / (1.f + expf(-z.y));
    g1[e] = ga; g2[e] = gb;
    int c = ei[NEDGES + e];
    atomicAdd(&deg1[c], ga);
    atomicAdd(&deg2[c], gb);
    atomicAdd(&cnt[c], 1);
}

// ---------------- deg -> rsqrt(deg) in place (deg >= 1 always)
__global__ void k_rsqrt(float* __restrict__ d1, float* __restrict__ d2) {
    int i = blockIdx.x * blockDim.x + threadIdx.x;
    if (i < NNODES) { d1[i] = rsqrtf(d1[i]); d2[i] = rsqrtf(d2[i]); }
}

// ---------------- scan phase 1: per-256-block exclusive scan + block sums
__global__ __launch_bounds__(256) void k_scan1(const int* __restrict__ cnt,
                                               int* __restrict__ offs,
                                               int* __restrict__ partial) {
    __shared__ int s[256];
    int t = threadIdx.x;
    int gid = blockIdx.x * 256 + t;
    int own = (gid < NNODES) ? cnt[gid] : 0;
    s[t] = own;
    __syncthreads();
    for (int off = 1; off < 256; off <<= 1) {
        int v = (t >= off) ? s[t - off] : 0;
        __syncthreads();
        s[t] += v;
        __syncthreads();
    }
    if (gid < NNODES) offs[gid] = s[t] - own;   // exclusive
    if (t == 255) partial[blockIdx.x] = s[255];
}

// ---------------- scan phase 2: single block scans the block sums (exclusive)
__global__ __launch_bounds__(512) void k_scan2(int* __restrict__ partial) {
    __shared__ int s[512];
    int t = threadIdx.x;
    int own = (t < NBLK_SCAN) ? partial[t] : 0;
    s[t] = own;
    __syncthreads();
    for (int off = 1; off < 512; off <<= 1) {
        int v = (t >= off) ? s[t - off] : 0;
        __syncthreads();
        s[t] += v;
        __syncthreads();
    }
    if (t < NBLK_SCAN) partial[t] = s[t] - own;  // exclusive
}

// ---------------- scan phase 3: add block offsets; init cursor; offs[N]=E
__global__ void k_scan3(int* __restrict__ offs, const int* __restrict__ partial,
                        int* __restrict__ cur) {
    int gid = blockIdx.x * blockDim.x + threadIdx.x;
    if (gid < NNODES) {
        int v = offs[gid] + partial[gid >> 8];
        offs[gid] = v;
        cur[gid] = v;
    }
    if (gid == 0) offs[NNODES] = NEDGES;
}

// ---------------- scatter edges into CSR slots + precompute per-layer norms
__global__ __launch_bounds__(256) void k_scatter(
    const int* __restrict__ ei, const float* __restrict__ g1,
    const float* __restrict__ g2, const float* __restrict__ dinv1,
    const float* __restrict__ dinv2, int* __restrict__ cur,
    int* __restrict__ prow, float* __restrict__ wl1, float* __restrict__ wl2) {
    int e = blockIdx.x * 256 + threadIdx.x;
    if (e >= NEDGES) return;
    int r = ei[e], c = ei[NEDGES + e];
    int pos = atomicAdd(&cur[c], 1);
    prow[pos] = r;
    wl1[pos] = dinv1[r] * g1[e] * dinv1[c];
    wl2[pos] = dinv2[r] * g2[e] * dinv2[c];
}

// ---------------- fp32 GEMM: Y[M,128] = act(X)[M,128] @ W[128,128]
template <int RELU>
__global__ __launch_bounds__(256) void k_gemm(const float* __restrict__ X,
                                              const float* __restrict__ W,
                                              float* __restrict__ Y, int M) {
    __shared__ __align__(16) float sX[64 * 68];
    __shared__ __align__(16) float sW[64 * 132];
    int t = threadIdx.x;
    int row0 = blockIdx.x * 64;
    int tx = t & 15, ty = t >> 4;

    float acc[4][8];
#pragma unroll
    for (int i = 0; i < 4; i++)
#pragma unroll
        for (int j = 0; j < 8; j++) acc[i][j] = 0.f;

    for (int kt = 0; kt < 128; kt += 64) {
        for (int i = t; i < 1024; i += 256) {
            int r = i >> 4, c4 = i & 15;
            float4 v = make_float4(0.f, 0.f, 0.f, 0.f);
            if (row0 + r < M) v = ((const float4*)X)[(size_t)(row0 + r) * 32 + (kt >> 2) + c4];
            if (RELU) {
                v.x = fmaxf(v.x, 0.f); v.y = fmaxf(v.y, 0.f);
                v.z = fmaxf(v.z, 0.f); v.w = fmaxf(v.w, 0.f);
            }
            ((float4*)(sX + r * 68))[c4] = v;
        }
        for (int i = t; i < 2048; i += 256) {
            int r = i >> 5, c4 = i & 31;
            float4 v = ((const float4*)W)[(size_t)(kt + r) * 32 + c4];
            ((float4*)(sW + r * 132))[c4] = v;
        }
        __syncthreads();
#pragma unroll 8
        for (int k = 0; k < 64; k++) {
            float xv[4];
#pragma unroll
            for (int i = 0; i < 4; i++) xv[i] = sX[(ty * 4 + i) * 68 + k];
            float4 wA = *(const float4*)(sW + k * 132 + tx * 4);
            float4 wB = *(const float4*)(sW + k * 132 + 64 + tx * 4);
#pragma unroll
            for (int i = 0; i < 4; i++) {
                acc[i][0] += xv[i] * wA.x; acc[i][1] += xv[i] * wA.y;
                acc[i][2] += xv[i] * wA.z; acc[i][3] += xv[i] * wA.w;
                acc[i][4] += xv[i] * wB.x; acc[i][5] += xv[i] * wB.y;
                acc[i][6] += xv[i] * wB.z; acc[i][7] += xv[i] * wB.w;
            }
        }
        __syncthreads();
    }
#pragma unroll
    for (int i = 0; i < 4; i++) {
        int r = row0 + ty * 4 + i;
        if (r < M) {
            float4 o1 = make_float4(acc[i][0], acc[i][1], acc[i][2], acc[i][3]);
            float4 o2 = make_float4(acc[i][4], acc[i][5], acc[i][6], acc[i][7]);
            *(float4*)(Y + (size_t)r * 128 + tx * 4) = o1;
            *(float4*)(Y + (size_t)r * 128 + 64 + tx * 4) = o2;
        }
    }
}

// ---------------- CSR aggregation: one wave per node, register accumulation.
__global__ __launch_bounds__(256) void k_aggcsr(
    const int* __restrict__ offs, const int* __restrict__ prow,
    const float* __restrict__ wl, const float* __restrict__ dinv,
    const float* __restrict__ h, float* __restrict__ out) {
    int node = blockIdx.x * 4 + (threadIdx.x >> 6);
    if (node >= NNODES) return;
    int lane = threadIdx.x & 63;
    int beg = offs[node], end = offs[node + 1];
    float d = dinv[node];
    float2 hv = ((const float2*)h)[(size_t)node * 64 + lane];
    float2 acc;
    acc.x = d * d * hv.x;
    acc.y = d * d * hv.y;
    int   r_n = 0; float w_n = 0.f;
    if (beg < end) { r_n = prow[beg]; w_n = wl[beg]; }
    for (int e = beg; e < end; e++) {
        int   r = r_n;
        float w = w_n;
        if (e + 1 < end) { r_n = prow[e + 1]; w_n = wl[e + 1]; }
        float2 v = ((const float2*)h)[(size_t)r * 64 + lane];
        acc.x += w * v.x;
        acc.y += w * v.y;
    }
    ((float2*)out)[(size_t)node * 64 + lane] = acc;
}

extern "C" void kernel_launch(void* const* d_in, const int* in_sizes, int n_in,
                              void* d_out, int out_size, void* d_ws, size_t ws_size,
                              hipStream_t stream) {
    const float* x    = (const float*)d_in[0];
    const int*   ei   = (const int*)d_in[1];
    const float* ea   = (const float*)d_in[2];
    const float* W1   = (const float*)d_in[3];
    const float* m1w1 = (const float*)d_in[4];
    const float* m1b1 = (const float*)d_in[5];
    const float* m1w2 = (const float*)d_in[6];
    const float* m1b2 = (const float*)d_in[7];
    const float* W2   = (const float*)d_in[8];
    const float* m2w1 = (const float*)d_in[9];
    const float* m2b1 = (const float*)d_in[10];
    const float* m2w2 = (const float*)d_in[11];
    const float* m2b2 = (const float*)d_in[12];
    float* out = (float*)d_out;

    float* ws    = (float*)d_ws;
    float* g1    = ws;                               // E
    float* g2    = g1 + NEDGES;                      // E
    float* deg1  = g2 + NEDGES;                      // N
    float* deg2  = deg1 + NNODES;                    // N
    float* hbuf  = deg2 + NNODES;                    // N*128
    float* aggbf = hbuf + (size_t)NNODES * 128;      // N*128
    float* wint  = aggbf + (size_t)NNODES * 128;     // 4096
    float* bw2   = wint + 4096;                      // 512
    float* wl1   = bw2 + 512;                        // E
    float* wl2   = wl1 + NEDGES;                     // E
    int*   cnt   = (int*)(wl2 + NEDGES);             // N (also cursor)
    int*   offs  = cnt + NNODES;                     // N+1
    int*   part  = offs + NNODES + 1;                // 1024
    int*   prow  = part + 1024;                      // E

    k_prep<<<18, 256, 0, stream>>>(m1w1, m2w1, m1b1, m2b1, m1w2, m2w2, wint, bw2);
    k_deg_init<<<(NNODES + 255) / 256, 256, 0, stream>>>(deg1, deg2, cnt);
    k_gates3<<<NEDGES / 256, 256, 0, stream>>>(ea, ei, wint, bw2, m1b2, m2b2,
                                               g1, g2, deg1, deg2, cnt);
    k_rsqrt<<<(NNODES + 255) / 256, 256, 0, stream>>>(deg1, deg2);

    // CSR build (graph shared by both layers)
    k_scan1<<<NBLK_SCAN, 256, 0, stream>>>(cnt, offs, part);
    k_scan2<<<1, 512, 0, stream>>>(part);
    k_scan3<<<(NNODES + 255) / 256, 256, 0, stream>>>(offs, part, cnt);
    k_scatter<<<NEDGES / 256, 256, 0, stream>>>(ei, g1, g2, deg1, deg2,
                                                cnt, prow, wl1, wl2);

    // layer 1
    k_gemm<0><<<(NNODES + 63) / 64, 256, 0, stream>>>(x, W1, hbuf, NNODES);
    k_aggcsr<<<(NNODES + 3) / 4, 256, 0, stream>>>(offs, prow, wl1, deg1, hbuf, aggbf);

    // layer 2 (relu fused into GEMM load)
    k_gemm<1><<<(NNODES + 63) / 64, 256, 0, stream>>>(aggbf, W2, hbuf, NNODES);
    k_aggcsr<<<(NNODES + 3) / 4, 256, 0, stream>>>(offs, prow, wl2, deg2, hbuf, out);
}